// Round 4
// baseline (346.884 us; speedup 1.0000x reference)
//
#include <hip/hip_runtime.h>

// y = W @ x + b ; W fp32 [8192,8192] (256 MiB) streamed once in memcpy order.
//
// R4: fewer, longer streams. 512 blocks; each owns 16 consecutive rows =
// one contiguous 512 KB chunk, read in pure sequential order (thread t,
// step s -> float4 index t+256s within the chunk): a 4-KB sliding front,
// 4x fewer concurrent DRAM streams than R3. 2 blocks/CU, 8 waves/CU.
// col4 = (t+256s) mod 2048 = t + 256*(s mod 8): each thread keeps 8
// x-float4s in registers, reused across all 16 rows. W loads nontemporal.

constexpr int IN_F  = 8192;
constexpr int OUT_F = 8192;
constexpr int ROWS_PER_BLOCK = 16;      // 512 KB contiguous chunk per block
constexpr int NT = 256;                 // threads per block (4 waves)

typedef float v4f __attribute__((ext_vector_type(4)));

__global__ __launch_bounds__(NT) void matvec_f32_kernel(
    const float* __restrict__ x,
    const float* __restrict__ W,
    const float* __restrict__ bias,
    float* __restrict__ y) {

  const int t = threadIdx.x;
  const int blk = blockIdx.x;

  const v4f* __restrict__ xv = reinterpret_cast<const v4f*>(x);
  const v4f* __restrict__ Wc = reinterpret_cast<const v4f*>(
      W + (size_t)blk * ROWS_PER_BLOCK * IN_F);

  // Per-thread x fragment: 8 float4 (coalesced, L2-resident), reused 16x.
  v4f xf[8];
#pragma unroll
  for (int j = 0; j < 8; ++j)
    xf[j] = xv[t + 256 * j];

  float acc[ROWS_PER_BLOCK];

#pragma unroll
  for (int r = 0; r < ROWS_PER_BLOCK; ++r) {
    // 8 nontemporal dwordx4 in flight per row-pass, memcpy-ordered.
    v4f w[8];
#pragma unroll
    for (int j = 0; j < 8; ++j)
      w[j] = __builtin_nontemporal_load(&Wc[t + 256 * (8 * r + j)]);

    float p0 = 0.f, p1 = 0.f;
#pragma unroll
    for (int j = 0; j < 8; ++j) {
      p0 += w[j].x * xf[j].x + w[j].z * xf[j].z;
      p1 += w[j].y * xf[j].y + w[j].w * xf[j].w;
    }
    acc[r] = p0 + p1;
  }

  // Reduce each row across the wave, then across the 4 waves via LDS.
  __shared__ float red[4][ROWS_PER_BLOCK];
  const int lane = t & 63;
  const int wave = t >> 6;

#pragma unroll
  for (int r = 0; r < ROWS_PER_BLOCK; ++r) {
    float v = acc[r];
#pragma unroll
    for (int off = 32; off > 0; off >>= 1)
      v += __shfl_down(v, off, 64);
    if (lane == 0) red[wave][r] = v;
  }
  __syncthreads();

  if (t < ROWS_PER_BLOCK) {
    float v = red[0][t] + red[1][t] + red[2][t] + red[3][t];
    y[blk * ROWS_PER_BLOCK + t] = v + bias[blk * ROWS_PER_BLOCK + t];
  }
}

extern "C" void kernel_launch(void* const* d_in, const int* in_sizes, int n_in,
                              void* d_out, int out_size, void* d_ws, size_t ws_size,
                              hipStream_t stream) {
  const float* x = (const float*)d_in[0];   // input  [8192]
  const float* W = (const float*)d_in[1];   // weight [8192*8192]
  const float* b = (const float*)d_in[2];   // bias   [8192]
  float* y = (float*)d_out;                 // output [8192] fp32

  dim3 grid(OUT_F / ROWS_PER_BLOCK);        // 512 blocks -> 2 blocks/CU
  dim3 block(NT);                           // 256 threads (4 waves)
  matvec_f32_kernel<<<grid, block, 0, stream>>>(x, W, b, y);
}